// Round 1
// baseline (5879.395 us; speedup 1.0000x reference)
//
#include <hip/hip_runtime.h>
#include <hip/hip_bf16.h>
#include <stdint.h>

#define B_    64
#define T_    512
#define NIN_  64
#define N_    1024
#define NOUT_ 32

// persistent-scan decomposition
#define NISL  16            // islands (independent batch groups)
#define BPI   16            // blocks per island (N-slices)
#define MB    4             // batches per island  = B_/NISL
#define COLS  64            // output cols per block = N_/BPI
#define NT    4             // 16-wide N tiles per block
#define KW    256           // K range per wave = N_/4
#define KT    8             // 32-wide K steps per wave

typedef float f32x4 __attribute__((ext_vector_type(4)));
typedef short s16x8 __attribute__((ext_vector_type(8)));

__device__ __forceinline__ unsigned short f2bf(float f) {
  union { float f; unsigned u; } v; v.f = f;
  unsigned r = v.u + 0x7FFFu + ((v.u >> 16) & 1u);   // RNE, no NaN in data
  return (unsigned short)(r >> 16);
}

__device__ __forceinline__ s16x8 pack4(unsigned a, unsigned b, unsigned c, unsigned d) {
  union { unsigned u[4]; s16x8 v; } x;
  x.u[0] = a; x.u[1] = b; x.u[2] = c; x.u[3] = d;
  return x.v;
}

// ---------------------------------------------------------------------------
// Persistent scan kernel: 256 blocks = 16 islands x 16 N-slices.
// Each wave holds its W_rec slice (1024x64 cols, K-range 256) as resident
// bf16 MFMA B-fragments (128 VGPRs). Per step: spin on island flag, load
// r_t fragments from the exchange buffer (agent atomics), MFMA, cross-wave
// LDS reduce, state update, publish r_{t+1}, post flag.
// ---------------------------------------------------------------------------
__global__ __launch_bounds__(256, 1) void rnn_scan(
    const float* __restrict__ U, const float* __restrict__ X0,
    const float* __restrict__ SN, const float* __restrict__ RN,
    const float* __restrict__ Wi, const float* __restrict__ Bi,
    const float* __restrict__ Wr,
    float* __restrict__ X, float* __restrict__ R,
    unsigned* __restrict__ flags, unsigned* __restrict__ ex)
{
  const int bid   = blockIdx.x;
  const int isl   = bid / BPI, slice = bid % BPI;
  const int tid   = threadIdx.x;
  const int wave  = tid >> 6, lane = tid & 63;
  const int l15   = lane & 15, koct = lane >> 4;
  const int colbase = slice * COLS;

  // --- resident B fragments of W_rec slice: B[k][n] = W_rec[col n][k] ---
  s16x8 bfrag[KT][NT];
#pragma unroll
  for (int kt = 0; kt < KT; ++kt) {
    const int k0 = wave * KW + kt * 32 + koct * 8;
#pragma unroll
    for (int nt = 0; nt < NT; ++nt) {
      const float* p = Wr + (size_t)(colbase + nt * 16 + l15) * N_ + k0;
      s16x8 f;
#pragma unroll
      for (int i = 0; i < 8; ++i) f[i] = (short)f2bf(p[i]);
      bfrag[kt][nt] = f;
    }
  }
  // --- W_in fragments (input term, handled by wave 0 as 2 extra K-steps) ---
  s16x8 wifrag[2][NT];
  if (wave == 0) {
#pragma unroll
    for (int kt = 0; kt < 2; ++kt) {
#pragma unroll
      for (int nt = 0; nt < NT; ++nt) {
        const float* p = Wi + (size_t)(colbase + nt * 16 + l15) * NIN_ + kt * 32 + koct * 8;
        s16x8 f;
#pragma unroll
        for (int i = 0; i < 8; ++i) f[i] = (short)f2bf(p[i]);
        wifrag[kt][nt] = f;
      }
    }
  }

  // thread (wave, lane) owns state element (batch = wave, col = lane)
  const int cc  = lane;
  const int bloc = wave;
  const int bg  = isl * MB + bloc;            // global batch
  const int nn  = colbase + cc;               // global col
  const int abatch = isl * MB + (l15 & (MB - 1)); // A-row batch (pad rows dup row 0-3)

  float x = X0[nn];
  const float bin = Bi[nn];
  const float r0 = fmaxf(tanhf(x), 0.f);

  __shared__ float part[4][MB][COLS];         // cross-wave K-partials

  unsigned* myflag = flags + isl * (T_ + 1);

  // publish r_0 into parity-0 exchange buffer
  {
    unsigned short h = f2bf(r0);
    unsigned other = __shfl_xor((unsigned)h, 1);
    if ((lane & 1) == 0)
      __hip_atomic_store(ex + (size_t)bg * (N_ / 2) + (nn >> 1),
                         (unsigned)h | (other << 16),
                         __ATOMIC_RELAXED, __HIP_MEMORY_SCOPE_AGENT);
  }
  __syncthreads();
  if (tid == 0)
    __hip_atomic_fetch_add(myflag, 1u, __ATOMIC_RELEASE, __HIP_MEMORY_SCOPE_AGENT);

  for (int t = 0; t < T_; ++t) {
    const int par = t & 1;
    const size_t row = (size_t)bg * T_ + t;
    // issue noise loads early; latency hides under the spin
    const float snv = SN[row * N_ + nn];
    const float rnv = RN[row * N_ + nn];
    s16x8 ua[2];
    if (wave == 0) {
      const size_t urow = ((size_t)(isl * MB + (l15 & (MB - 1))) * T_ + t) * NIN_;
#pragma unroll
      for (int kt = 0; kt < 2; ++kt) {
        const float* p = U + urow + kt * 32 + koct * 8;
        s16x8 f;
#pragma unroll
        for (int i = 0; i < 8; ++i) f[i] = (short)f2bf(p[i]);
        ua[kt] = f;
      }
    }
    // wait for all island slices of r_t
    if (tid == 0) {
      while (__hip_atomic_load(myflag + t, __ATOMIC_ACQUIRE, __HIP_MEMORY_SCOPE_AGENT) < BPI)
        __builtin_amdgcn_s_sleep(1);
    }
    __syncthreads();

    // A fragments: r_t[batch][k], 8 bf16 per lane = 4 packed u32 agent loads
    const unsigned* exr = ex + (size_t)par * (B_ * (N_ / 2));
    f32x4 acc[NT];
#pragma unroll
    for (int nt = 0; nt < NT; ++nt) acc[nt] = f32x4{0.f, 0.f, 0.f, 0.f};
    s16x8 afr[KT];
#pragma unroll
    for (int kt = 0; kt < KT; ++kt) {
      const int k0 = wave * KW + kt * 32 + koct * 8;
      const unsigned* p = exr + (size_t)abatch * (N_ / 2) + (k0 >> 1);
      unsigned q0 = __hip_atomic_load(p + 0, __ATOMIC_RELAXED, __HIP_MEMORY_SCOPE_AGENT);
      unsigned q1 = __hip_atomic_load(p + 1, __ATOMIC_RELAXED, __HIP_MEMORY_SCOPE_AGENT);
      unsigned q2 = __hip_atomic_load(p + 2, __ATOMIC_RELAXED, __HIP_MEMORY_SCOPE_AGENT);
      unsigned q3 = __hip_atomic_load(p + 3, __ATOMIC_RELAXED, __HIP_MEMORY_SCOPE_AGENT);
      afr[kt] = pack4(q0, q1, q2, q3);
    }
#pragma unroll
    for (int kt = 0; kt < KT; ++kt)
#pragma unroll
      for (int nt = 0; nt < NT; ++nt)
        acc[nt] = __builtin_amdgcn_mfma_f32_16x16x32_bf16(afr[kt], bfrag[kt][nt], acc[nt], 0, 0, 0);
    if (wave == 0) {
#pragma unroll
      for (int kt = 0; kt < 2; ++kt)
#pragma unroll
        for (int nt = 0; nt < NT; ++nt)
          acc[nt] = __builtin_amdgcn_mfma_f32_16x16x32_bf16(ua[kt], wifrag[kt][nt], acc[nt], 0, 0, 0);
    }
    // write per-wave K-partials: D rows 0..3 live in lanes 0..15, reg = row
    if (lane < 16) {
#pragma unroll
      for (int nt = 0; nt < NT; ++nt)
#pragma unroll
        for (int r = 0; r < MB; ++r)
          part[wave][r][nt * 16 + lane] = acc[nt][r];
    }
    __syncthreads();
    const float mat = part[0][bloc][cc] + part[1][bloc][cc] +
                      part[2][bloc][cc] + part[3][bloc][cc];
    const float xn = x + 0.1f * (-x + mat + bin + snv);
    const float rv = fmaxf(tanhf(xn), 0.f) + rnv;
    x = xn;
    // publish r_{t+1}
    {
      unsigned short h = f2bf(rv);
      unsigned other = __shfl_xor((unsigned)h, 1);
      if ((lane & 1) == 0)
        __hip_atomic_store(ex + (size_t)(par ^ 1) * (B_ * (N_ / 2)) +
                               (size_t)bg * (N_ / 2) + (nn >> 1),
                           (unsigned)h | (other << 16),
                           __ATOMIC_RELAXED, __HIP_MEMORY_SCOPE_AGENT);
    }
    __syncthreads();   // drains exchange stores (vmcnt) for all waves
    if (tid == 0)
      __hip_atomic_fetch_add(myflag + t + 1, 1u, __ATOMIC_RELEASE, __HIP_MEMORY_SCOPE_AGENT);
    // X/R stores AFTER the flag post: their HBM latency is off the sync path
    X[row * N_ + nn] = xn;
    R[row * N_ + nn] = rv;
  }
}

// ---------------------------------------------------------------------------
// Z = R @ W_out^T + b_out + output_noise.  W_out register-resident per thread
// (o = tid&31, kc = tid>>5 owns W_out[o][kc*128..+128)); R row staged in LDS.
// ---------------------------------------------------------------------------
#define TCH 128
__global__ __launch_bounds__(256, 1) void rnn_zout(
    const float* __restrict__ Rm, const float* __restrict__ ON,
    const float* __restrict__ Wo, const float* __restrict__ Bo,
    float* __restrict__ Z)
{
  const int bid = blockIdx.x;
  const int b = bid >> 2, tq = bid & 3;
  const int tid = threadIdx.x;
  const int o = tid & 31, kc = tid >> 5;

  float4 wv[32];
  const float4* wp = (const float4*)(Wo + (size_t)o * N_ + kc * 128);
#pragma unroll
  for (int i = 0; i < 32; ++i) wv[i] = wp[i];

  __shared__ float Rl[N_];
  __shared__ float zred[8][32];

  for (int t = tq * TCH; t < tq * TCH + TCH; ++t) {
    const size_t row = (size_t)b * T_ + t;
    ((float4*)Rl)[tid] = ((const float4*)(Rm + row * N_))[tid];
    __syncthreads();
    float a0 = 0.f;
#pragma unroll
    for (int i = 0; i < 32; ++i) {
      const float* rp = Rl + kc * 128 + i * 4;
      a0 += wv[i].x * rp[0] + wv[i].y * rp[1] + wv[i].z * rp[2] + wv[i].w * rp[3];
    }
    zred[kc][o] = a0;
    __syncthreads();
    if (tid < 32) {
      float z = Bo[tid];
#pragma unroll
      for (int k = 0; k < 8; ++k) z += zred[k][tid];
      Z[row * NOUT_ + tid] = z + ON[row * NOUT_ + tid];
    }
    // no 3rd barrier needed: zred(t+1) writes are gated by the next
    // post-stage __syncthreads, which the reducer reaches only after reading.
  }
}

extern "C" void kernel_launch(void* const* d_in, const int* in_sizes, int n_in,
                              void* d_out, int out_size, void* d_ws, size_t ws_size,
                              hipStream_t stream) {
  const float* U  = (const float*)d_in[0];
  const float* X0 = (const float*)d_in[1];
  const float* SN = (const float*)d_in[2];
  const float* RN = (const float*)d_in[3];
  const float* ON = (const float*)d_in[4];
  const float* Wi = (const float*)d_in[5];
  const float* Bi = (const float*)d_in[6];
  const float* Wr = (const float*)d_in[7];
  const float* Wo = (const float*)d_in[8];
  const float* Bo = (const float*)d_in[9];

  float* X = (float*)d_out;
  float* R = X + (size_t)B_ * T_ * N_;
  float* Z = R + (size_t)B_ * T_ * N_;

  unsigned* flags = (unsigned*)d_ws;                       // [NISL][T_+1]
  unsigned* ex    = (unsigned*)((char*)d_ws + 65536);      // [2][B_][N_/2] bf16x2

  // reset flags every call (graph-capture-safe)
  hipMemsetAsync(flags, 0, NISL * (T_ + 1) * sizeof(unsigned), stream);

  hipLaunchKernelGGL(rnn_scan, dim3(NISL * BPI), dim3(256), 0, stream,
                     U, X0, SN, RN, Wi, Bi, Wr, X, R, flags, ex);
  hipLaunchKernelGGL(rnn_zout, dim3(B_ * (T_ / TCH)), dim3(256), 0, stream,
                     R, ON, Wo, Bo, Z);
}

// Round 2
// 1582.823 us; speedup vs baseline: 3.7145x; 3.7145x over previous
//
#include <hip/hip_runtime.h>
#include <hip/hip_bf16.h>
#include <stdint.h>

#define B_    64
#define T_    512
#define NIN_  64
#define N_    1024
#define NOUT_ 32

// persistent-scan decomposition
#define NISL  16            // islands (independent batch groups)
#define BPI   16            // blocks per island (N-slices)
#define MB    4             // batches per island  = B_/NISL
#define COLS  64            // output cols per block = N_/BPI
#define NT    4             // 16-wide N tiles per block
#define KW    256           // K range per wave = N_/4
#define KT    8             // 32-wide K steps per wave

typedef float f32x4 __attribute__((ext_vector_type(4)));
typedef short s16x8 __attribute__((ext_vector_type(8)));

__device__ __forceinline__ unsigned short f2bf(float f) {
  union { float f; unsigned u; } v; v.f = f;
  unsigned r = v.u + 0x7FFFu + ((v.u >> 16) & 1u);   // RNE, no NaN in data
  return (unsigned short)(r >> 16);
}

// 16B exchange read, bypassing L1/L2 (coherence-point fresh, no buffer_inv
// needed because ALL ex accesses are sc1 write-through / sc1 loads).
__device__ __forceinline__ s16x8 ld_ex16(const unsigned* p) {
  s16x8 r;
  asm volatile("global_load_dwordx4 %0, %1, off sc1"
               : "=v"(r) : "v"(p) : "memory");
  return r;
}

// ---------------------------------------------------------------------------
// Persistent scan: 256 blocks = 16 islands x 16 N-slices, W_rec resident in
// VGPRs. Hand-rolled release/acquire: relaxed flag atomics only (NO compiler
// fences -> no buffer_inv / buffer_wbl2 on the critical path). Visibility is
// guaranteed by sc1 write-through stores + the vmcnt(0) drain inside
// __syncthreads before the flag post, and sc1 loads on the consumer side.
// ---------------------------------------------------------------------------
__global__ __launch_bounds__(256, 1) void rnn_scan(
    const float* __restrict__ U, const float* __restrict__ X0,
    const float* __restrict__ SN, const float* __restrict__ RN,
    const float* __restrict__ Wi, const float* __restrict__ Bi,
    const float* __restrict__ Wr,
    float* __restrict__ X, float* __restrict__ R,
    unsigned* __restrict__ flags, unsigned* __restrict__ ex)
{
  const int bid   = blockIdx.x;
  const int isl   = bid / BPI, slice = bid % BPI;
  const int tid   = threadIdx.x;
  const int wave  = tid >> 6, lane = tid & 63;
  const int l15   = lane & 15, koct = lane >> 4;
  const int colbase = slice * COLS;

  // --- resident B fragments of W_rec slice: B[k][n] = W_rec[col n][k] ---
  s16x8 bfrag[KT][NT];
#pragma unroll
  for (int kt = 0; kt < KT; ++kt) {
    const int k0 = wave * KW + kt * 32 + koct * 8;
#pragma unroll
    for (int nt = 0; nt < NT; ++nt) {
      const float* p = Wr + (size_t)(colbase + nt * 16 + l15) * N_ + k0;
      s16x8 f;
#pragma unroll
      for (int i = 0; i < 8; ++i) f[i] = (short)f2bf(p[i]);
      bfrag[kt][nt] = f;
    }
  }
  // --- W_in fragments: input term split across waves 0,1 (K=64 = 2x32) ---
  s16x8 wifrag[NT];
  if (wave < 2) {
#pragma unroll
    for (int nt = 0; nt < NT; ++nt) {
      const float* p = Wi + (size_t)(colbase + nt * 16 + l15) * NIN_ + wave * 32 + koct * 8;
      s16x8 f;
#pragma unroll
      for (int i = 0; i < 8; ++i) f[i] = (short)f2bf(p[i]);
      wifrag[nt] = f;
    }
  }

  // thread (wave, lane) owns state element (batch = wave, col = lane)
  const int cc  = lane;
  const int bloc = wave;
  const int bg  = isl * MB + bloc;                 // global batch
  const int nn  = colbase + cc;                    // global col
  const int abatch = isl * MB + (l15 & (MB - 1));  // A-row batch (rows dup 4x)

  float x = X0[nn];
  const float bin = Bi[nn];
  const float r0 = fmaxf(tanhf(x), 0.f);

  __shared__ float part[4][COLS][MB];              // [wave][col][batch]

  unsigned* const myflags = flags + isl * (T_ + 1);

  // publish r_0 into parity-0 exchange buffer (sc1 write-through atomics)
  {
    unsigned short h = f2bf(r0);
    unsigned other = __shfl_xor((unsigned)h, 1);
    if ((lane & 1) == 0)
      __hip_atomic_store(ex + (size_t)bg * (N_ / 2) + (nn >> 1),
                         (unsigned)h | (other << 16),
                         __ATOMIC_RELAXED, __HIP_MEMORY_SCOPE_AGENT);
  }
  __syncthreads();   // drains vmcnt for all waves -> ex visible at IF$
  if (tid == 0)
    __hip_atomic_fetch_add(myflags, 1u, __ATOMIC_RELAXED, __HIP_MEMORY_SCOPE_AGENT);

  float pxn = 0.f, prv = 0.f;                      // deferred X/R store values

  for (int t = 0; t < T_; ++t) {
    const int par = t & 1;
    const size_t row = (size_t)bg * T_ + t;

    // independent loads issued before the wait (latency hides under spin)
    const float snv = SN[row * N_ + nn];
    const float rnv = RN[row * N_ + nn];
    s16x8 ua;
    if (wave < 2) {
      const float* p = U + ((size_t)(isl * MB + (l15 & (MB - 1))) * T_ + t) * NIN_
                         + wave * 32 + koct * 8;
#pragma unroll
      for (int i = 0; i < 8; ++i) ua[i] = (short)f2bf(p[i]);
    }

    // per-wave relaxed poll (no buffer_inv; sc1 load is coherence-fresh)
    while (__hip_atomic_load(myflags + t, __ATOMIC_RELAXED, __HIP_MEMORY_SCOPE_AGENT) < BPI)
      __builtin_amdgcn_s_sleep(2);

    // previous step's X/R stores: issued here so their HBM ack overlaps the
    // exchange-load latency instead of sitting on the laggard's poll drain
    if (t > 0) {
      X[(row - 1) * N_ + nn] = pxn;
      R[(row - 1) * N_ + nn] = prv;
    }

    // A fragments: vectorized sc1 loads from exchange buffer
    const unsigned* exr = ex + (size_t)par * (B_ * (N_ / 2))
                             + (size_t)abatch * (N_ / 2);
    s16x8 afr[KT];
#pragma unroll
    for (int kt = 0; kt < KT; ++kt)
      afr[kt] = ld_ex16(exr + ((wave * KW + kt * 32 + koct * 8) >> 1));
    asm volatile("s_waitcnt vmcnt(0)" ::: "memory");
    __builtin_amdgcn_sched_barrier(0);   // rule #18: keep MFMA below the wait

    f32x4 acc[NT];
#pragma unroll
    for (int nt = 0; nt < NT; ++nt) acc[nt] = f32x4{0.f, 0.f, 0.f, 0.f};
#pragma unroll
    for (int kt = 0; kt < KT; ++kt)
#pragma unroll
      for (int nt = 0; nt < NT; ++nt)
        acc[nt] = __builtin_amdgcn_mfma_f32_16x16x32_bf16(afr[kt], bfrag[kt][nt], acc[nt], 0, 0, 0);
    if (wave < 2) {
#pragma unroll
      for (int nt = 0; nt < NT; ++nt)
        acc[nt] = __builtin_amdgcn_mfma_f32_16x16x32_bf16(ua, wifrag[nt], acc[nt], 0, 0, 0);
    }

    // cross-wave K-partials: D rows 0..3 (= island batches) live in lanes<16,
    // reg r = row. part[w][col][r] gives a contiguous b128 write per lane.
    if (lane < 16) {
#pragma unroll
      for (int nt = 0; nt < NT; ++nt)
        *(f32x4*)&part[wave][nt * 16 + lane][0] = acc[nt];
    }
    __syncthreads();
    const float mat = part[0][cc][bloc] + part[1][cc][bloc] +
                      part[2][cc][bloc] + part[3][cc][bloc];
    const float xn = x + 0.1f * (-x + mat + bin + snv);
    const float rv = fmaxf(tanhf(xn), 0.f) + rnv;
    x = xn;

    // publish r_{t+1} (sc1 write-through)
    {
      unsigned short h = f2bf(rv);
      unsigned other = __shfl_xor((unsigned)h, 1);
      if ((lane & 1) == 0)
        __hip_atomic_store(ex + (size_t)(par ^ 1) * (B_ * (N_ / 2)) +
                               (size_t)bg * (N_ / 2) + (nn >> 1),
                           (unsigned)h | (other << 16),
                           __ATOMIC_RELAXED, __HIP_MEMORY_SCOPE_AGENT);
    }
    __syncthreads();   // drains all waves' ex stores (vmcnt) before the post
    if (tid == 0)
      __hip_atomic_fetch_add(myflags + t + 1, 1u, __ATOMIC_RELAXED, __HIP_MEMORY_SCOPE_AGENT);

    pxn = xn; prv = rv;
  }
  // final deferred store
  {
    const size_t lrow = (size_t)bg * T_ + (T_ - 1);
    X[lrow * N_ + nn] = pxn;
    R[lrow * N_ + nn] = prv;
  }
}

// ---------------------------------------------------------------------------
// Z = R @ W_out^T + b_out + output_noise.  W_out register-resident per thread
// (o = tid&31, kc = tid>>5 owns W_out[o][kc*128..+128)); R row staged in LDS.
// ---------------------------------------------------------------------------
#define TCH 128
__global__ __launch_bounds__(256, 1) void rnn_zout(
    const float* __restrict__ Rm, const float* __restrict__ ON,
    const float* __restrict__ Wo, const float* __restrict__ Bo,
    float* __restrict__ Z)
{
  const int bid = blockIdx.x;
  const int b = bid >> 2, tq = bid & 3;
  const int tid = threadIdx.x;
  const int o = tid & 31, kc = tid >> 5;

  float4 wv[32];
  const float4* wp = (const float4*)(Wo + (size_t)o * N_ + kc * 128);
#pragma unroll
  for (int i = 0; i < 32; ++i) wv[i] = wp[i];

  __shared__ float Rl[N_];
  __shared__ float zred[8][32];

  for (int t = tq * TCH; t < tq * TCH + TCH; ++t) {
    const size_t row = (size_t)b * T_ + t;
    ((float4*)Rl)[tid] = ((const float4*)(Rm + row * N_))[tid];
    __syncthreads();
    float a0 = 0.f;
#pragma unroll
    for (int i = 0; i < 32; ++i) {
      const float* rp = Rl + kc * 128 + i * 4;
      a0 += wv[i].x * rp[0] + wv[i].y * rp[1] + wv[i].z * rp[2] + wv[i].w * rp[3];
    }
    zred[kc][o] = a0;
    __syncthreads();
    if (tid < 32) {
      float z = Bo[tid];
#pragma unroll
      for (int k = 0; k < 8; ++k) z += zred[k][tid];
      Z[row * NOUT_ + tid] = z + ON[row * NOUT_ + tid];
    }
    // no 3rd barrier needed: zred(t+1) writes are gated by the next
    // post-stage __syncthreads, which the reducer reaches only after reading.
  }
}

extern "C" void kernel_launch(void* const* d_in, const int* in_sizes, int n_in,
                              void* d_out, int out_size, void* d_ws, size_t ws_size,
                              hipStream_t stream) {
  const float* U  = (const float*)d_in[0];
  const float* X0 = (const float*)d_in[1];
  const float* SN = (const float*)d_in[2];
  const float* RN = (const float*)d_in[3];
  const float* ON = (const float*)d_in[4];
  const float* Wi = (const float*)d_in[5];
  const float* Bi = (const float*)d_in[6];
  const float* Wr = (const float*)d_in[7];
  const float* Wo = (const float*)d_in[8];
  const float* Bo = (const float*)d_in[9];

  float* X = (float*)d_out;
  float* R = X + (size_t)B_ * T_ * N_;
  float* Z = R + (size_t)B_ * T_ * N_;

  unsigned* flags = (unsigned*)d_ws;                       // [NISL][T_+1]
  unsigned* ex    = (unsigned*)((char*)d_ws + 65536);      // [2][B_][N_/2] bf16x2

  // reset flags every call (graph-capture-safe)
  hipMemsetAsync(flags, 0, NISL * (T_ + 1) * sizeof(unsigned), stream);

  hipLaunchKernelGGL(rnn_scan, dim3(NISL * BPI), dim3(256), 0, stream,
                     U, X0, SN, RN, Wi, Bi, Wr, X, R, flags, ex);
  hipLaunchKernelGGL(rnn_zout, dim3(B_ * (T_ / TCH)), dim3(256), 0, stream,
                     R, ON, Wo, Bo, Z);
}